// Round 9
// baseline (556.378 us; speedup 1.0000x reference)
//
#include <hip/hip_runtime.h>

#define W 1024
#define H 1024
#define NPIX (H * W)
#define NSTEP 5                 // fused steps per launch
#define LROWS 18                // local rows per strip (8 net + 2*5 halo)
#define NETR 8                  // net rows per strip
#define NETC 54                 // net cols per wave (64 - 2*5)
#define NTILE 19                // ceil(1024/54) col tiles
#define NSTRIP 128              // 1024/8 row strips
#define NWAVE (NTILE * NSTRIP)  // 2432 waves = grid (1 wave per block)

__device__ __forceinline__ float frcp_(float v) { return __builtin_amdgcn_rcpf(v); }
__device__ __forceinline__ float sigm_(float v) { return frcp_(1.0f + __expf(-v)); }
__device__ __forceinline__ float tanh_(float v) {
    return 1.0f - 2.0f * frcp_(1.0f + __expf(2.0f * v));
}

// 5 fused conv-LSTM steps, wave-autonomous (NO __syncthreads anywhere).
// Block = 1 wave (64 threads). Lane owns one column gc = 54*t - 5 + lane;
// strip s owns net rows [8s, 8s+8), local rows j=0..17 <-> global r0-5+j.
// h,c state in wave-private LDS [LROWS][64]; vertical conv via a rolling
// 3-row register window; horizontal h neighbors via ds_read lane+-1 (64B
// guard rows absorb edge spill), x neighbors via __shfl. Step i computes
// rows j in [i, 18-i) (fresh-region shrink == stencil pollution); cols
// valid [i, 64-i), so after 5 steps rows [5,13) x lanes [5,59) are exact.
// All global accesses bounds-masked: no padded buffers, x read straight
// from the input frames; out-of-image h := 0 reproduces SAME zero-padding.
__global__ __launch_bounds__(64, 4) void lstm5(
    const float* __restrict__ xb, long xstep,
    const float* __restrict__ hin, const float* __restrict__ cin,
    float* __restrict__ hout, float* __restrict__ cout_,
    const float* __restrict__ wg, const float* __restrict__ bg,
    float* __restrict__ dout, int zero_init)
{
    __shared__ float Hs[(LROWS + 2) * 64];   // +2 guard rows (idx 0, LROWS+1)
    __shared__ float Cs[LROWS * 64];
    const int lane = threadIdx.x;
    const int s = blockIdx.x & (NSTRIP - 1);
    const int t = blockIdx.x >> 7;
    const int r0 = s * NETR;
    const int gc = t * NETC - NSTEP + lane;
    const bool colok = (unsigned)gc < (unsigned)W;

    // zero guard rows (their values only feed discarded halo lanes)
    Hs[lane] = 0.f;
    Hs[(LROWS + 1) * 64 + lane] = 0.f;

    // ---- initial state rows (bounds-masked; zero_init skips loads) ----
    for (int j = 0; j < LROWS; ++j) {
        float hv = 0.f, cv = 0.f;
        const int gr = r0 - NSTEP + j;
        if (!zero_init && colok && (unsigned)gr < (unsigned)H) {
            hv = hin[gr * W + gc];
            cv = cin[gr * W + gc];
        }
        Hs[(1 + j) * 64 + lane] = hv;
        Cs[j * 64 + lane] = cv;
    }

    for (int i = 1; i <= NSTEP; ++i) {
        const float* xf = xb + (long)(i - 1) * xstep;
        // preload window rows i-1 (m) and i (z)
        int gr = r0 - NSTEP + (i - 1);
        float xv_m = (colok && (unsigned)gr < (unsigned)H) ? xf[gr * W + gc] : 0.f;
        float xl_m = __shfl_up(xv_m, 1), xr_m = __shfl_down(xv_m, 1);
        gr = r0 - NSTEP + i;
        float xv_z = (colok && (unsigned)gr < (unsigned)H) ? xf[gr * W + gc] : 0.f;
        float xl_z = __shfl_up(xv_z, 1), xr_z = __shfl_down(xv_z, 1);
        int hb = i * 64 + lane;                 // LDS idx of row i-1 (= 1+(i-1))
        float hv_m = Hs[hb], hl_m = Hs[hb - 1], hr_m = Hs[hb + 1];
        hb = (i + 1) * 64 + lane;               // row i
        float hv_z = Hs[hb], hl_z = Hs[hb - 1], hr_z = Hs[hb + 1];

        for (int j = i; j <= LROWS - 1 - i; ++j) {
            // load window row j+1 (p)
            gr = r0 - NSTEP + j + 1;
            float xv_p = (colok && (unsigned)gr < (unsigned)H) ? xf[gr * W + gc] : 0.f;
            float xl_p = __shfl_up(xv_p, 1), xr_p = __shfl_down(xv_p, 1);
            hb = (j + 2) * 64 + lane;           // row j+1 (old value: not yet written)
            float hv_p = Hs[hb], hl_p = Hs[hb - 1], hr_p = Hs[hb + 1];
            float cc = Cs[j * 64 + lane];

            float av[4];
#pragma unroll
            for (int g = 0; g < 4; ++g) {
                const float* wp = wg + g * 18;
                av[g] = bg[g]
                    + wp[0]  * xl_m + wp[1]  * xv_m + wp[2]  * xr_m
                    + wp[3]  * xl_z + wp[4]  * xv_z + wp[5]  * xr_z
                    + wp[6]  * xl_p + wp[7]  * xv_p + wp[8]  * xr_p
                    + wp[9]  * hl_m + wp[10] * hv_m + wp[11] * hr_m
                    + wp[12] * hl_z + wp[13] * hv_z + wp[14] * hr_z
                    + wp[15] * hl_p + wp[16] * hv_p + wp[17] * hr_p;
            }
            const int go = r0 - NSTEP + j;
            const bool ok = colok && (unsigned)go < (unsigned)H;
            const float cn = sigm_(av[1]) * cc + sigm_(av[0]) * tanh_(av[3]);
            const float hh = ok ? (sigm_(av[2]) * tanh_(cn)) : 0.f;  // SAME pad
            Cs[j * 64 + lane] = cn;
            Hs[(1 + j) * 64 + lane] = hh;       // old H[j] preserved in window regs

            // rotate windows m <- z <- p
            xl_m = xl_z; xv_m = xv_z; xr_m = xr_z;
            xl_z = xl_p; xv_z = xv_p; xr_z = xr_p;
            hl_m = hl_z; hv_m = hv_z; hr_m = hr_z;
            hl_z = hl_p; hv_z = hv_p; hr_z = hr_p;
        }
    }

    // ---- store net region: rows j=5..12 (global r0..r0+7), lanes [5,59) ----
    if (lane >= NSTEP && lane < NSTEP + NETC && colok) {
        if (dout) {
            for (int j = NSTEP; j < NSTEP + NETR; ++j) {
                const int gr = r0 - NSTEP + j;
                dout[gr * W + gc] = Hs[(1 + j) * 64 + lane];
            }
        } else {
            for (int j = NSTEP; j < NSTEP + NETR; ++j) {
                const int gr = r0 - NSTEP + j;
                hout[gr * W + gc]  = Hs[(1 + j) * 64 + lane];
                cout_[gr * W + gc] = Cs[j * 64 + lane];
            }
        }
    }
}

extern "C" void kernel_launch(void* const* d_in, const int* in_sizes, int n_in,
                              void* d_out, int out_size, void* d_ws, size_t ws_size,
                              hipStream_t stream) {
    const float* data  = (const float*)d_in[0];  // [20,1,1,1024,1024]
    const float* enc_w = (const float*)d_in[1];  // [4,2,3,3]
    const float* enc_b = (const float*)d_in[2];  // [4]
    const float* dec_w = (const float*)d_in[3];
    const float* dec_b = (const float*)d_in[4];
    // d_in[5..7] = epoch(0), T_en(20), T_de(20): constant device scalars;
    // loop counts hardcoded (host can't read device memory under capture).

    float* ws = (float*)d_ws;                    // 6 unpadded 1024^2 buffers
    float* hA = ws + 0 * (size_t)NPIX;
    float* cA = ws + 1 * (size_t)NPIX;
    float* hB = ws + 2 * (size_t)NPIX;
    float* cB = ws + 3 * (size_t)NPIX;
    float* hC = ws + 4 * (size_t)NPIX;
    float* cC = ws + 5 * (size_t)NPIX;
    float* dout = (float*)d_out;
    // no init kernel: every launch fully rewrites the net region it hands on;
    // halo/out-of-image reads are bounds-masked to zero in-kernel.

    dim3 blk(64), grd(NWAVE);
    // encoder: 4 x 5 steps over data frames
    lstm5<<<grd, blk, 0, stream>>>(data,             (long)NPIX, nullptr, nullptr,
                                   hA, cA, enc_w, enc_b, nullptr, 1);
    lstm5<<<grd, blk, 0, stream>>>(data +  5 * (size_t)NPIX, (long)NPIX, hA, cA,
                                   hB, cB, enc_w, enc_b, nullptr, 0);
    lstm5<<<grd, blk, 0, stream>>>(data + 10 * (size_t)NPIX, (long)NPIX, hB, cB,
                                   hA, cA, enc_w, enc_b, nullptr, 0);
    lstm5<<<grd, blk, 0, stream>>>(data + 15 * (size_t)NPIX, (long)NPIX, hA, cA,
                                   hB, cB, enc_w, enc_b, nullptr, 0);
    // final encoder h in hB = constant decoder input (zero outside = SAME pad)
    lstm5<<<grd, blk, 0, stream>>>(hB, 0, nullptr, nullptr,
                                   hA, cA, dec_w, dec_b, nullptr, 1);
    lstm5<<<grd, blk, 0, stream>>>(hB, 0, hA, cA,
                                   hC, cC, dec_w, dec_b, nullptr, 0);
    lstm5<<<grd, blk, 0, stream>>>(hB, 0, hC, cC,
                                   hA, cA, dec_w, dec_b, nullptr, 0);
    lstm5<<<grd, blk, 0, stream>>>(hB, 0, hA, cA,
                                   hC, cC, dec_w, dec_b, dout, 0);
}